// Round 8
// baseline (744.569 us; speedup 1.0000x reference)
//
#include <hip/hip_runtime.h>
#include <hip/hip_bf16.h>

typedef _Float16 f16x8 __attribute__((ext_vector_type(8)));
typedef float    f32x4 __attribute__((ext_vector_type(4)));
typedef float    f32x2 __attribute__((ext_vector_type(2)));

#define T_STEPS 1024
#define BATCH   128
#define DH      256
#define BH      (BATCH * DH)

// ---------------------------------------------------------------------------
// Kernel 1 (unchanged, ~87us): xp = x @ W_ih^T + b_ih + b_hh -> d_out.
// f16 hi/lo split (3 MFMA passes) => ~fp32 accuracy.
// ---------------------------------------------------------------------------
#define BM 128
#define BN 128
#define BK 64

__device__ __forceinline__ void stage_tile(const float* __restrict__ src,
                                           int row0, int kc,
                                           unsigned short* hi, unsigned short* lo,
                                           int t) {
#pragma unroll
  for (int i = 0; i < 8; ++i) {
    int f   = i * 256 + t;
    int row = f >> 4;
    int q   = f & 15;
    const float4 v = *(const float4*)&src[(size_t)(row0 + row) * 256 + kc + q * 4];
    _Float16 h0 = (_Float16)v.x, h1 = (_Float16)v.y,
             h2 = (_Float16)v.z, h3 = (_Float16)v.w;
    _Float16 l0 = (_Float16)(v.x - (float)h0), l1 = (_Float16)(v.y - (float)h1),
             l2 = (_Float16)(v.z - (float)h2), l3 = (_Float16)(v.w - (float)h3);
    unsigned int off = (unsigned int)(row * 128 + q * 8) ^ ((row & 7) << 4);
    union { _Float16 h[4]; uint2 u; } ph, pl;
    ph.h[0] = h0; ph.h[1] = h1; ph.h[2] = h2; ph.h[3] = h3;
    pl.h[0] = l0; pl.h[1] = l1; pl.h[2] = l2; pl.h[3] = l3;
    *(uint2*)((char*)hi + off) = ph.u;
    *(uint2*)((char*)lo + off) = pl.u;
  }
}

__global__ __launch_bounds__(256, 2) void xp_gemm(
    const float* __restrict__ x,   const float* __restrict__ Wih,
    const float* __restrict__ bih, const float* __restrict__ bhh,
    float* __restrict__ out) {
  __shared__ __align__(16) unsigned short Ah[BM * BK], Al[BM * BK];
  __shared__ __align__(16) unsigned short Bh[BN * BK], Bl[BN * BK];
  const int t    = threadIdx.x;
  const int m0   = blockIdx.x * BM;
  const int n0   = blockIdx.y * BN;
  const int lane = t & 63;
  const int wave = t >> 6;
  const int wm = wave >> 1, wn = wave & 1;

  f32x4 acc[4][4];
#pragma unroll
  for (int i = 0; i < 4; ++i)
#pragma unroll
    for (int j = 0; j < 4; ++j) acc[i][j] = (f32x4)0.0f;

  for (int kc = 0; kc < 256; kc += BK) {
    stage_tile(x,   m0, kc, Ah, Al, t);
    stage_tile(Wih, n0, kc, Bh, Bl, t);
    __syncthreads();
#pragma unroll
    for (int ks = 0; ks < 2; ++ks) {
      f16x8 ah[4], al[4], bh[4], bl[4];
#pragma unroll
      for (int mi = 0; mi < 4; ++mi) {
        int row = wm * 64 + mi * 16 + (lane & 15);
        unsigned int off =
            (unsigned int)(row * 128 + ks * 64 + ((lane >> 4) << 4)) ^ ((row & 7) << 4);
        ah[mi] = *(const f16x8*)((const char*)Ah + off);
        al[mi] = *(const f16x8*)((const char*)Al + off);
      }
#pragma unroll
      for (int ni = 0; ni < 4; ++ni) {
        int row = wn * 64 + ni * 16 + (lane & 15);
        unsigned int off =
            (unsigned int)(row * 128 + ks * 64 + ((lane >> 4) << 4)) ^ ((row & 7) << 4);
        bh[ni] = *(const f16x8*)((const char*)Bh + off);
        bl[ni] = *(const f16x8*)((const char*)Bl + off);
      }
#pragma unroll
      for (int mi = 0; mi < 4; ++mi)
#pragma unroll
        for (int ni = 0; ni < 4; ++ni) {
          acc[mi][ni] = __builtin_amdgcn_mfma_f32_16x16x32_f16(ah[mi], bh[ni], acc[mi][ni], 0, 0, 0);
          acc[mi][ni] = __builtin_amdgcn_mfma_f32_16x16x32_f16(ah[mi], bl[ni], acc[mi][ni], 0, 0, 0);
          acc[mi][ni] = __builtin_amdgcn_mfma_f32_16x16x32_f16(al[mi], bh[ni], acc[mi][ni], 0, 0, 0);
        }
    }
    __syncthreads();
  }
#pragma unroll
  for (int ni = 0; ni < 4; ++ni) {
    int col = n0 + wn * 64 + ni * 16 + (lane & 15);
    float bias = bih[col] + bhh[col];
#pragma unroll
    for (int mi = 0; mi < 4; ++mi) {
      int rbase = m0 + wm * 64 + mi * 16 + ((lane >> 4) << 2);
#pragma unroll
      for (int r = 0; r < 4; ++r)
        out[(size_t)(rbase + r) * DH + col] = acc[mi][ni][r] + bias;
    }
  }
}

// ---------------------------------------------------------------------------
// Kernel 2: recurrence = R5 structure (PASSING, 646us) + two changes:
//  (1) loop barrier = raw "s_waitcnt lgkmcnt(0); s_barrier" (one asm block,
//      "memory" clobber). __syncthreads drains vmcnt(0) every step, exposing
//      the full retire latency of the global h-store + xp prefetch at the
//      barrier (~half the step time). Only the LDS hs write needs ordering
//      (lgkmcnt). Global stores now pipeline across steps (T4 principle:
//      never drain vmcnt in the main loop). In-place xp-read/h-write hazard
//      is same-lane same-address: enforced by dataflow (store value depends
//      on the load), no fence needed.
//  (2) xp prefetch 2-deep (step time shrinks toward ~900cy ~= HBM latency,
//      1-deep becomes marginal).
// Geometry (R5, verified): 512 thr, 8 waves pinned 2/EU. Thread (wv, r, c):
// 8 outputs jb=wv*32+r*8 over k-slice {64q+4c+e}. 4x ds_read_b128 h
// (stride-1, conflict-free). 64x v_pk_fma_f32. dpp_ror butterfly over 16
// c-lanes (VALU pipe). Lanes c<8 write h.
// ---------------------------------------------------------------------------
__device__ __forceinline__ float tanh_fast(float x) {
  float xc = fminf(9.0f, fmaxf(-9.0f, x));
  float e2 = __builtin_amdgcn_exp2f(2.885390082f * xc);
  return 1.0f - 2.0f * __builtin_amdgcn_rcpf(e2 + 1.0f);
}

__device__ __forceinline__ float dpp_ror_sum16(float x) {
  float y;
  asm("v_add_f32_dpp %0, %1, %1 row_ror:8 row_mask:0xf bank_mask:0xf"
      : "=v"(y) : "v"(x));
  asm("v_add_f32_dpp %0, %1, %1 row_ror:4 row_mask:0xf bank_mask:0xf"
      : "=v"(x) : "v"(y));
  asm("v_add_f32_dpp %0, %1, %1 row_ror:2 row_mask:0xf bank_mask:0xf"
      : "=v"(y) : "v"(x));
  asm("v_add_f32_dpp %0, %1, %1 row_ror:1 row_mask:0xf bank_mask:0xf"
      : "=v"(x) : "v"(y));
  return x;
}

#define PKMUL(a, w, h) \
  asm("v_pk_mul_f32 %0, %1, %2"     : "=v"(a) : "v"(w), "v"(h))
#define PKFMA(a, w, h) \
  asm("v_pk_fma_f32 %0, %1, %2, %0" : "+v"(a) : "v"(w), "v"(h))

// LDS-only barrier: order hs writes/reads across waves WITHOUT draining vmcnt
// (global stores/loads keep flying). One asm block so the compiler cannot
// separate the wait from the barrier or move memory ops across (lesson #18).
#define LDS_BARRIER() \
  asm volatile("s_waitcnt lgkmcnt(0)\n\ts_barrier" ::: "memory")

__attribute__((amdgpu_waves_per_eu(2, 2)))
__global__ __launch_bounds__(512) void rnn_rec(
    const float* __restrict__ Whh, float* __restrict__ xh) {
  const int b    = blockIdx.x;
  const int t    = threadIdx.x;
  const int lane = t & 63;
  const int wv   = t >> 6;        // 0..7
  const int r    = lane >> 4;     // 0..3
  const int c    = lane & 15;     // 0..15
  const int jb   = wv * 32 + r * 8;

  __shared__ __align__(16) float hs[2][DH];

  // W rows jb..jb+7, k-slice {64q+4c..+3} -> 64 f32x2 (k-pairs)
  f32x2 w2[8][8];
#pragma unroll
  for (int j = 0; j < 8; ++j)
#pragma unroll
    for (int q = 0; q < 4; ++q) {
      float4 v = *(const float4*)&Whh[(size_t)(jb + j) * DH + 64 * q + 4 * c];
      f32x2 lo; lo[0] = v.x; lo[1] = v.y;
      f32x2 hi; hi[0] = v.z; hi[1] = v.w;
      w2[j][2 * q]     = lo;
      w2[j][2 * q + 1] = hi;
    }

  const bool writer = (c < 8);
  const int  j      = jb + (c & 7);
  float* pcol = xh + (size_t)b * DH + j;
  const char* hb0 = (const char*)&hs[0][0] + 16 * c;
  const char* hb1 = (const char*)&hs[1][0] + 16 * c;

  if (t < DH) hs[0][t] = 0.0f;
  float xpc = 0.0f, xp1 = 0.0f;
  if (writer) { xpc = pcol[0]; xp1 = pcol[BH]; }   // steps 0,1
  __syncthreads();

#define STEP(S, P)                                                             \
  {                                                                            \
    float xp2 = 0.0f;                                                          \
    if (writer && (S) + 2 < T_STEPS)                                           \
      xp2 = pcol[((size_t)(S) + 2) * BH];          /* 2-deep prefetch */       \
    const char* hb = (P) ? hb1 : hb0;                                          \
    float4 hq0 = *(const float4*)(hb);                                         \
    float4 hq1 = *(const float4*)(hb + 256);                                   \
    float4 hq2 = *(const float4*)(hb + 512);                                   \
    float4 hq3 = *(const float4*)(hb + 768);                                   \
    f32x2 hp[8];                                                               \
    hp[0][0] = hq0.x; hp[0][1] = hq0.y;  hp[1][0] = hq0.z; hp[1][1] = hq0.w;   \
    hp[2][0] = hq1.x; hp[2][1] = hq1.y;  hp[3][0] = hq1.z; hp[3][1] = hq1.w;   \
    hp[4][0] = hq2.x; hp[4][1] = hq2.y;  hp[5][0] = hq2.z; hp[5][1] = hq2.w;   \
    hp[6][0] = hq3.x; hp[6][1] = hq3.y;  hp[7][0] = hq3.z; hp[7][1] = hq3.w;   \
    f32x2 acc[8];                                                              \
    _Pragma("unroll")                                                          \
    for (int jj = 0; jj < 8; ++jj) PKMUL(acc[jj], w2[jj][0], hp[0]);           \
    _Pragma("unroll")                                                          \
    for (int kp = 1; kp < 8; ++kp)                                             \
      _Pragma("unroll")                                                        \
      for (int jj = 0; jj < 8; ++jj) PKFMA(acc[jj], w2[jj][kp], hp[kp]);       \
    float a[8];                                                                \
    _Pragma("unroll")                                                          \
    for (int jj = 0; jj < 8; ++jj) a[jj] = acc[jj][0] + acc[jj][1];            \
    _Pragma("unroll")                                                          \
    for (int jj = 0; jj < 8; ++jj) a[jj] = dpp_ror_sum16(a[jj]);               \
    const int cc = c & 7;                                                      \
    float v0 = (cc & 1) ? a[1] : a[0];                                         \
    float v1 = (cc & 1) ? a[3] : a[2];                                         \
    float v2 = (cc & 1) ? a[5] : a[4];                                         \
    float v3 = (cc & 1) ? a[7] : a[6];                                         \
    float u0 = (cc & 2) ? v1 : v0;                                             \
    float u1 = (cc & 2) ? v3 : v2;                                             \
    float sum = (cc & 4) ? u1 : u0;                                            \
    float h = tanh_fast(sum + xpc);                                            \
    if (writer) {                                                              \
      hs[(P) ^ 1][j] = h;                                                      \
      pcol[(size_t)(S) * BH] = h;                                              \
    }                                                                          \
    xpc = xp1; xp1 = xp2;                                                      \
    LDS_BARRIER();                                                             \
  }

  for (int s = 0; s < T_STEPS; s += 2) {
    STEP(s, 0)
    STEP(s + 1, 1)
  }
#undef STEP
}

extern "C" void kernel_launch(void* const* d_in, const int* in_sizes, int n_in,
                              void* d_out, int out_size, void* d_ws, size_t ws_size,
                              hipStream_t stream) {
  const float* x   = (const float*)d_in[0];
  const float* Wih = (const float*)d_in[1];
  const float* Whh = (const float*)d_in[2];
  const float* bih = (const float*)d_in[3];
  const float* bhh = (const float*)d_in[4];
  float* out = (float*)d_out;

  dim3 g1((T_STEPS * BATCH) / BM, DH / BN);   // 1024 x 2
  xp_gemm<<<g1, dim3(256), 0, stream>>>(x, Wih, bih, bhh, out);
  rnn_rec<<<BATCH, dim3(512), 0, stream>>>(Whh, out);
}

// Round 9
// 731.190 us; speedup vs baseline: 1.0183x; 1.0183x over previous
//
#include <hip/hip_runtime.h>
#include <hip/hip_bf16.h>

typedef _Float16 f16x8 __attribute__((ext_vector_type(8)));
typedef float    f32x4 __attribute__((ext_vector_type(4)));
typedef float    f32x2 __attribute__((ext_vector_type(2)));

#define T_STEPS 1024
#define BATCH   128
#define DH      256
#define BH      (BATCH * DH)

// ---------------------------------------------------------------------------
// Kernel 1 (unchanged, ~87us): xp = x @ W_ih^T + b_ih + b_hh -> d_out.
// f16 hi/lo split (3 MFMA passes) => ~fp32 accuracy.
// ---------------------------------------------------------------------------
#define BM 128
#define BN 128
#define BK 64

__device__ __forceinline__ void stage_tile(const float* __restrict__ src,
                                           int row0, int kc,
                                           unsigned short* hi, unsigned short* lo,
                                           int t) {
#pragma unroll
  for (int i = 0; i < 8; ++i) {
    int f   = i * 256 + t;
    int row = f >> 4;
    int q   = f & 15;
    const float4 v = *(const float4*)&src[(size_t)(row0 + row) * 256 + kc + q * 4];
    _Float16 h0 = (_Float16)v.x, h1 = (_Float16)v.y,
             h2 = (_Float16)v.z, h3 = (_Float16)v.w;
    _Float16 l0 = (_Float16)(v.x - (float)h0), l1 = (_Float16)(v.y - (float)h1),
             l2 = (_Float16)(v.z - (float)h2), l3 = (_Float16)(v.w - (float)h3);
    unsigned int off = (unsigned int)(row * 128 + q * 8) ^ ((row & 7) << 4);
    union { _Float16 h[4]; uint2 u; } ph, pl;
    ph.h[0] = h0; ph.h[1] = h1; ph.h[2] = h2; ph.h[3] = h3;
    pl.h[0] = l0; pl.h[1] = l1; pl.h[2] = l2; pl.h[3] = l3;
    *(uint2*)((char*)hi + off) = ph.u;
    *(uint2*)((char*)lo + off) = pl.u;
  }
}

__global__ __launch_bounds__(256, 2) void xp_gemm(
    const float* __restrict__ x,   const float* __restrict__ Wih,
    const float* __restrict__ bih, const float* __restrict__ bhh,
    float* __restrict__ out) {
  __shared__ __align__(16) unsigned short Ah[BM * BK], Al[BM * BK];
  __shared__ __align__(16) unsigned short Bh[BN * BK], Bl[BN * BK];
  const int t    = threadIdx.x;
  const int m0   = blockIdx.x * BM;
  const int n0   = blockIdx.y * BN;
  const int lane = t & 63;
  const int wave = t >> 6;
  const int wm = wave >> 1, wn = wave & 1;

  f32x4 acc[4][4];
#pragma unroll
  for (int i = 0; i < 4; ++i)
#pragma unroll
    for (int j = 0; j < 4; ++j) acc[i][j] = (f32x4)0.0f;

  for (int kc = 0; kc < 256; kc += BK) {
    stage_tile(x,   m0, kc, Ah, Al, t);
    stage_tile(Wih, n0, kc, Bh, Bl, t);
    __syncthreads();
#pragma unroll
    for (int ks = 0; ks < 2; ++ks) {
      f16x8 ah[4], al[4], bh[4], bl[4];
#pragma unroll
      for (int mi = 0; mi < 4; ++mi) {
        int row = wm * 64 + mi * 16 + (lane & 15);
        unsigned int off =
            (unsigned int)(row * 128 + ks * 64 + ((lane >> 4) << 4)) ^ ((row & 7) << 4);
        ah[mi] = *(const f16x8*)((const char*)Ah + off);
        al[mi] = *(const f16x8*)((const char*)Al + off);
      }
#pragma unroll
      for (int ni = 0; ni < 4; ++ni) {
        int row = wn * 64 + ni * 16 + (lane & 15);
        unsigned int off =
            (unsigned int)(row * 128 + ks * 64 + ((lane >> 4) << 4)) ^ ((row & 7) << 4);
        bh[ni] = *(const f16x8*)((const char*)Bh + off);
        bl[ni] = *(const f16x8*)((const char*)Bl + off);
      }
#pragma unroll
      for (int mi = 0; mi < 4; ++mi)
#pragma unroll
        for (int ni = 0; ni < 4; ++ni) {
          acc[mi][ni] = __builtin_amdgcn_mfma_f32_16x16x32_f16(ah[mi], bh[ni], acc[mi][ni], 0, 0, 0);
          acc[mi][ni] = __builtin_amdgcn_mfma_f32_16x16x32_f16(ah[mi], bl[ni], acc[mi][ni], 0, 0, 0);
          acc[mi][ni] = __builtin_amdgcn_mfma_f32_16x16x32_f16(al[mi], bh[ni], acc[mi][ni], 0, 0, 0);
        }
    }
    __syncthreads();
  }
#pragma unroll
  for (int ni = 0; ni < 4; ++ni) {
    int col = n0 + wn * 64 + ni * 16 + (lane & 15);
    float bias = bih[col] + bhh[col];
#pragma unroll
    for (int mi = 0; mi < 4; ++mi) {
      int rbase = m0 + wm * 64 + mi * 16 + ((lane >> 4) << 2);
#pragma unroll
      for (int r = 0; r < 4; ++r)
        out[(size_t)(rbase + r) * DH + col] = acc[mi][ni][r] + bias;
    }
  }
}

// ---------------------------------------------------------------------------
// Kernel 2: recurrence = R8 geometry, but the FMA block is PLAIN C vector
// math (f32x2 * / __builtin_elementwise_fma) instead of "v"-pinned inline
// asm. Rationale (R8 counters): VGPR_Count=88 < 128 W floats => W lives in
// AGPRs; the "v" constraints forced per-use AGPR<->VGPR traffic / hazards
// that appeared as ~500cy/step of stall, not as VALU issue. Plain C lets the
// compiler read AGPRs directly as v_pk_fma operands (legal on CDNA4) and
// software-pipeline lgkmcnt waits into the FMA stream. DPP reduce stays asm
// (cross-lane, VGPR temporaries only).
// Geometry: 512 thr, 8 waves pinned 2/EU. Thread (wv, r, c): 8 outputs
// jb=wv*32+r*8 over k-slice {64q+4c+e}. 4x ds_read_b128 h (stride-1,
// conflict-free, 4-way same-addr broadcast across r). dpp_ror butterfly over
// 16 c-lanes. Lanes c<8 write h. LDS-only barrier; 2-deep xp prefetch.
// ---------------------------------------------------------------------------
__device__ __forceinline__ float tanh_fast(float x) {
  float xc = fminf(9.0f, fmaxf(-9.0f, x));
  float e2 = __builtin_amdgcn_exp2f(2.885390082f * xc);
  return 1.0f - 2.0f * __builtin_amdgcn_rcpf(e2 + 1.0f);
}

__device__ __forceinline__ float dpp_ror_sum16(float x) {
  float y;
  asm("v_add_f32_dpp %0, %1, %1 row_ror:8 row_mask:0xf bank_mask:0xf"
      : "=v"(y) : "v"(x));
  asm("v_add_f32_dpp %0, %1, %1 row_ror:4 row_mask:0xf bank_mask:0xf"
      : "=v"(x) : "v"(y));
  asm("v_add_f32_dpp %0, %1, %1 row_ror:2 row_mask:0xf bank_mask:0xf"
      : "=v"(y) : "v"(x));
  asm("v_add_f32_dpp %0, %1, %1 row_ror:1 row_mask:0xf bank_mask:0xf"
      : "=v"(x) : "v"(y));
  return x;
}

// LDS-only barrier (order hs across waves; global ops keep flying).
#define LDS_BARRIER() \
  asm volatile("s_waitcnt lgkmcnt(0)\n\ts_barrier" ::: "memory")

__attribute__((amdgpu_waves_per_eu(2, 2)))
__global__ __launch_bounds__(512) void rnn_rec(
    const float* __restrict__ Whh, float* __restrict__ xh) {
  const int b    = blockIdx.x;
  const int t    = threadIdx.x;
  const int lane = t & 63;
  const int wv   = t >> 6;        // 0..7
  const int r    = lane >> 4;     // 0..3
  const int c    = lane & 15;     // 0..15
  const int jb   = wv * 32 + r * 8;

  __shared__ __align__(16) float hs[2][DH];

  // W rows jb..jb+7, k-slice {64q+4c..+3} -> 64 f32x2 (k-pairs)
  f32x2 w2[8][8];
#pragma unroll
  for (int j = 0; j < 8; ++j)
#pragma unroll
    for (int q = 0; q < 4; ++q) {
      float4 v = *(const float4*)&Whh[(size_t)(jb + j) * DH + 64 * q + 4 * c];
      f32x2 lo; lo[0] = v.x; lo[1] = v.y;
      f32x2 hi; hi[0] = v.z; hi[1] = v.w;
      w2[j][2 * q]     = lo;
      w2[j][2 * q + 1] = hi;
    }

  const bool writer = (c < 8);
  const int  j      = jb + (c & 7);
  float* pcol = xh + (size_t)b * DH + j;
  const char* hb0 = (const char*)&hs[0][0] + 16 * c;
  const char* hb1 = (const char*)&hs[1][0] + 16 * c;

  if (t < DH) hs[0][t] = 0.0f;
  float xpc = 0.0f, xp1 = 0.0f;
  if (writer) { xpc = pcol[0]; xp1 = pcol[BH]; }   // steps 0,1
  __syncthreads();

#define STEP(S, P)                                                             \
  {                                                                            \
    float xp2 = 0.0f;                                                          \
    if (writer && (S) + 2 < T_STEPS)                                           \
      xp2 = pcol[((size_t)(S) + 2) * BH];          /* 2-deep prefetch */       \
    const char* hb = (P) ? hb1 : hb0;                                          \
    float4 hq0 = *(const float4*)(hb);                                         \
    float4 hq1 = *(const float4*)(hb + 256);                                   \
    float4 hq2 = *(const float4*)(hb + 512);                                   \
    float4 hq3 = *(const float4*)(hb + 768);                                   \
    f32x2 hp[8];                                                               \
    hp[0][0] = hq0.x; hp[0][1] = hq0.y;  hp[1][0] = hq0.z; hp[1][1] = hq0.w;   \
    hp[2][0] = hq1.x; hp[2][1] = hq1.y;  hp[3][0] = hq1.z; hp[3][1] = hq1.w;   \
    hp[4][0] = hq2.x; hp[4][1] = hq2.y;  hp[5][0] = hq2.z; hp[5][1] = hq2.w;   \
    hp[6][0] = hq3.x; hp[6][1] = hq3.y;  hp[7][0] = hq3.z; hp[7][1] = hq3.w;   \
    f32x2 acc[8];                                                              \
    _Pragma("unroll")                                                          \
    for (int jj = 0; jj < 8; ++jj) acc[jj] = w2[jj][0] * hp[0];                \
    _Pragma("unroll")                                                          \
    for (int kp = 1; kp < 8; ++kp)                                             \
      _Pragma("unroll")                                                        \
      for (int jj = 0; jj < 8; ++jj)                                           \
        acc[jj] = __builtin_elementwise_fma(w2[jj][kp], hp[kp], acc[jj]);      \
    float a[8];                                                                \
    _Pragma("unroll")                                                          \
    for (int jj = 0; jj < 8; ++jj) a[jj] = acc[jj][0] + acc[jj][1];            \
    _Pragma("unroll")                                                          \
    for (int jj = 0; jj < 8; ++jj) a[jj] = dpp_ror_sum16(a[jj]);               \
    const int cc = c & 7;                                                      \
    float v0 = (cc & 1) ? a[1] : a[0];                                         \
    float v1 = (cc & 1) ? a[3] : a[2];                                         \
    float v2 = (cc & 1) ? a[5] : a[4];                                         \
    float v3 = (cc & 1) ? a[7] : a[6];                                         \
    float u0 = (cc & 2) ? v1 : v0;                                             \
    float u1 = (cc & 2) ? v3 : v2;                                             \
    float sum = (cc & 4) ? u1 : u0;                                            \
    float h = tanh_fast(sum + xpc);                                            \
    if (writer) {                                                              \
      hs[(P) ^ 1][j] = h;                                                      \
      pcol[(size_t)(S) * BH] = h;                                              \
    }                                                                          \
    xpc = xp1; xp1 = xp2;                                                      \
    LDS_BARRIER();                                                             \
  }

  for (int s = 0; s < T_STEPS; s += 2) {
    STEP(s, 0)
    STEP(s + 1, 1)
  }
#undef STEP
}

extern "C" void kernel_launch(void* const* d_in, const int* in_sizes, int n_in,
                              void* d_out, int out_size, void* d_ws, size_t ws_size,
                              hipStream_t stream) {
  const float* x   = (const float*)d_in[0];
  const float* Wih = (const float*)d_in[1];
  const float* Whh = (const float*)d_in[2];
  const float* bih = (const float*)d_in[3];
  const float* bhh = (const float*)d_in[4];
  float* out = (float*)d_out;

  dim3 g1((T_STEPS * BATCH) / BM, DH / BN);   // 1024 x 2
  xp_gemm<<<g1, dim3(256), 0, stream>>>(x, Wih, bih, bhh, out);
  rnn_rec<<<BATCH, dim3(512), 0, stream>>>(Whh, out);
}

// Round 10
// 731.068 us; speedup vs baseline: 1.0185x; 1.0002x over previous
//
#include <hip/hip_runtime.h>
#include <hip/hip_bf16.h>

typedef _Float16 f16x8 __attribute__((ext_vector_type(8)));
typedef float    f32x4 __attribute__((ext_vector_type(4)));
typedef float    f32x2 __attribute__((ext_vector_type(2)));

#define T_STEPS 1024
#define BATCH   128
#define DH      256
#define BH      (BATCH * DH)

// ---------------------------------------------------------------------------
// Kernel 1 (unchanged, ~87us): xp = x @ W_ih^T + b_ih + b_hh -> d_out.
// f16 hi/lo split (3 MFMA passes) => ~fp32 accuracy.
// ---------------------------------------------------------------------------
#define BM 128
#define BN 128
#define BK 64

__device__ __forceinline__ void stage_tile(const float* __restrict__ src,
                                           int row0, int kc,
                                           unsigned short* hi, unsigned short* lo,
                                           int t) {
#pragma unroll
  for (int i = 0; i < 8; ++i) {
    int f   = i * 256 + t;
    int row = f >> 4;
    int q   = f & 15;
    const float4 v = *(const float4*)&src[(size_t)(row0 + row) * 256 + kc + q * 4];
    _Float16 h0 = (_Float16)v.x, h1 = (_Float16)v.y,
             h2 = (_Float16)v.z, h3 = (_Float16)v.w;
    _Float16 l0 = (_Float16)(v.x - (float)h0), l1 = (_Float16)(v.y - (float)h1),
             l2 = (_Float16)(v.z - (float)h2), l3 = (_Float16)(v.w - (float)h3);
    unsigned int off = (unsigned int)(row * 128 + q * 8) ^ ((row & 7) << 4);
    union { _Float16 h[4]; uint2 u; } ph, pl;
    ph.h[0] = h0; ph.h[1] = h1; ph.h[2] = h2; ph.h[3] = h3;
    pl.h[0] = l0; pl.h[1] = l1; pl.h[2] = l2; pl.h[3] = l3;
    *(uint2*)((char*)hi + off) = ph.u;
    *(uint2*)((char*)lo + off) = pl.u;
  }
}

__global__ __launch_bounds__(256, 2) void xp_gemm(
    const float* __restrict__ x,   const float* __restrict__ Wih,
    const float* __restrict__ bih, const float* __restrict__ bhh,
    float* __restrict__ out) {
  __shared__ __align__(16) unsigned short Ah[BM * BK], Al[BM * BK];
  __shared__ __align__(16) unsigned short Bh[BN * BK], Bl[BN * BK];
  const int t    = threadIdx.x;
  const int m0   = blockIdx.x * BM;
  const int n0   = blockIdx.y * BN;
  const int lane = t & 63;
  const int wave = t >> 6;
  const int wm = wave >> 1, wn = wave & 1;

  f32x4 acc[4][4];
#pragma unroll
  for (int i = 0; i < 4; ++i)
#pragma unroll
    for (int j = 0; j < 4; ++j) acc[i][j] = (f32x4)0.0f;

  for (int kc = 0; kc < 256; kc += BK) {
    stage_tile(x,   m0, kc, Ah, Al, t);
    stage_tile(Wih, n0, kc, Bh, Bl, t);
    __syncthreads();
#pragma unroll
    for (int ks = 0; ks < 2; ++ks) {
      f16x8 ah[4], al[4], bh[4], bl[4];
#pragma unroll
      for (int mi = 0; mi < 4; ++mi) {
        int row = wm * 64 + mi * 16 + (lane & 15);
        unsigned int off =
            (unsigned int)(row * 128 + ks * 64 + ((lane >> 4) << 4)) ^ ((row & 7) << 4);
        ah[mi] = *(const f16x8*)((const char*)Ah + off);
        al[mi] = *(const f16x8*)((const char*)Al + off);
      }
#pragma unroll
      for (int ni = 0; ni < 4; ++ni) {
        int row = wn * 64 + ni * 16 + (lane & 15);
        unsigned int off =
            (unsigned int)(row * 128 + ks * 64 + ((lane >> 4) << 4)) ^ ((row & 7) << 4);
        bh[ni] = *(const f16x8*)((const char*)Bh + off);
        bl[ni] = *(const f16x8*)((const char*)Bl + off);
      }
#pragma unroll
      for (int mi = 0; mi < 4; ++mi)
#pragma unroll
        for (int ni = 0; ni < 4; ++ni) {
          acc[mi][ni] = __builtin_amdgcn_mfma_f32_16x16x32_f16(ah[mi], bh[ni], acc[mi][ni], 0, 0, 0);
          acc[mi][ni] = __builtin_amdgcn_mfma_f32_16x16x32_f16(ah[mi], bl[ni], acc[mi][ni], 0, 0, 0);
          acc[mi][ni] = __builtin_amdgcn_mfma_f32_16x16x32_f16(al[mi], bh[ni], acc[mi][ni], 0, 0, 0);
        }
    }
    __syncthreads();
  }
#pragma unroll
  for (int ni = 0; ni < 4; ++ni) {
    int col = n0 + wn * 64 + ni * 16 + (lane & 15);
    float bias = bih[col] + bhh[col];
#pragma unroll
    for (int mi = 0; mi < 4; ++mi) {
      int rbase = m0 + wm * 64 + mi * 16 + ((lane >> 4) << 2);
#pragma unroll
      for (int r = 0; r < 4; ++r)
        out[(size_t)(rbase + r) * DH + col] = acc[mi][ni][r] + bias;
    }
  }
}

// ---------------------------------------------------------------------------
// Kernel 2: recurrence. IDENTICAL compute to R9. ONE experimental variable:
// a ~100KB dummy LDS block forces LDS_Block_Size ~102KB > 160-102 => the HW
// CANNOT co-schedule a second WG on the CU. Theory: the universal ~650-850us
// across 6 structurally different kernels = WG co-location doubling per-CU
// issue (2 batches interleaved on shared SIMDs; kernel waits for the doubled
// CUs). Bottom-up single-WG step ~=760cy; measured 1514 ~= exactly 2x.
// ---------------------------------------------------------------------------
__device__ __forceinline__ float tanh_fast(float x) {
  float xc = fminf(9.0f, fmaxf(-9.0f, x));
  float e2 = __builtin_amdgcn_exp2f(2.885390082f * xc);
  return 1.0f - 2.0f * __builtin_amdgcn_rcpf(e2 + 1.0f);
}

__device__ __forceinline__ float dpp_ror_sum16(float x) {
  float y;
  asm("v_add_f32_dpp %0, %1, %1 row_ror:8 row_mask:0xf bank_mask:0xf"
      : "=v"(y) : "v"(x));
  asm("v_add_f32_dpp %0, %1, %1 row_ror:4 row_mask:0xf bank_mask:0xf"
      : "=v"(x) : "v"(y));
  asm("v_add_f32_dpp %0, %1, %1 row_ror:2 row_mask:0xf bank_mask:0xf"
      : "=v"(y) : "v"(x));
  asm("v_add_f32_dpp %0, %1, %1 row_ror:1 row_mask:0xf bank_mask:0xf"
      : "=v"(x) : "v"(y));
  return x;
}

// LDS-only barrier (order hs across waves; global ops keep flying).
#define LDS_BARRIER() \
  asm volatile("s_waitcnt lgkmcnt(0)\n\ts_barrier" ::: "memory")

__attribute__((amdgpu_waves_per_eu(2, 2)))
__global__ __launch_bounds__(512) void rnn_rec(
    const float* __restrict__ Whh, float* __restrict__ xh) {
  const int b    = blockIdx.x;
  const int t    = threadIdx.x;
  const int lane = t & 63;
  const int wv   = t >> 6;        // 0..7
  const int r    = lane >> 4;     // 0..3
  const int c    = lane & 15;     // 0..15
  const int jb   = wv * 32 + r * 8;

  __shared__ __align__(16) float hs[2][DH];
  // --- co-location blocker: ~100KB of LDS so only ONE WG fits per CU ---
  __shared__ float lds_pad[25000];
  if (t == 0) lds_pad[b & 1023] = 0.0f;   // touch so it isn't eliminated

  // W rows jb..jb+7, k-slice {64q+4c..+3} -> 64 f32x2 (k-pairs)
  f32x2 w2[8][8];
#pragma unroll
  for (int j = 0; j < 8; ++j)
#pragma unroll
    for (int q = 0; q < 4; ++q) {
      float4 v = *(const float4*)&Whh[(size_t)(jb + j) * DH + 64 * q + 4 * c];
      f32x2 lo; lo[0] = v.x; lo[1] = v.y;
      f32x2 hi; hi[0] = v.z; hi[1] = v.w;
      w2[j][2 * q]     = lo;
      w2[j][2 * q + 1] = hi;
    }

  const bool writer = (c < 8);
  const int  j      = jb + (c & 7);
  float* pcol = xh + (size_t)b * DH + j;
  const char* hb0 = (const char*)&hs[0][0] + 16 * c;
  const char* hb1 = (const char*)&hs[1][0] + 16 * c;

  if (t < DH) hs[0][t] = 0.0f;
  float xpc = 0.0f, xp1 = 0.0f;
  if (writer) { xpc = pcol[0]; xp1 = pcol[BH]; }   // steps 0,1
  __syncthreads();

#define STEP(S, P)                                                             \
  {                                                                            \
    float xp2 = 0.0f;                                                          \
    if (writer && (S) + 2 < T_STEPS)                                           \
      xp2 = pcol[((size_t)(S) + 2) * BH];          /* 2-deep prefetch */       \
    const char* hb = (P) ? hb1 : hb0;                                          \
    float4 hq0 = *(const float4*)(hb);                                         \
    float4 hq1 = *(const float4*)(hb + 256);                                   \
    float4 hq2 = *(const float4*)(hb + 512);                                   \
    float4 hq3 = *(const float4*)(hb + 768);                                   \
    f32x2 hp[8];                                                               \
    hp[0][0] = hq0.x; hp[0][1] = hq0.y;  hp[1][0] = hq0.z; hp[1][1] = hq0.w;   \
    hp[2][0] = hq1.x; hp[2][1] = hq1.y;  hp[3][0] = hq1.z; hp[3][1] = hq1.w;   \
    hp[4][0] = hq2.x; hp[4][1] = hq2.y;  hp[5][0] = hq2.z; hp[5][1] = hq2.w;   \
    hp[6][0] = hq3.x; hp[6][1] = hq3.y;  hp[7][0] = hq3.z; hp[7][1] = hq3.w;   \
    f32x2 acc[8];                                                              \
    _Pragma("unroll")                                                          \
    for (int jj = 0; jj < 8; ++jj) acc[jj] = w2[jj][0] * hp[0];                \
    _Pragma("unroll")                                                          \
    for (int kp = 1; kp < 8; ++kp)                                             \
      _Pragma("unroll")                                                        \
      for (int jj = 0; jj < 8; ++jj)                                           \
        acc[jj] = __builtin_elementwise_fma(w2[jj][kp], hp[kp], acc[jj]);      \
    float a[8];                                                                \
    _Pragma("unroll")                                                          \
    for (int jj = 0; jj < 8; ++jj) a[jj] = acc[jj][0] + acc[jj][1];            \
    _Pragma("unroll")                                                          \
    for (int jj = 0; jj < 8; ++jj) a[jj] = dpp_ror_sum16(a[jj]);               \
    const int cc = c & 7;                                                      \
    float v0 = (cc & 1) ? a[1] : a[0];                                         \
    float v1 = (cc & 1) ? a[3] : a[2];                                         \
    float v2 = (cc & 1) ? a[5] : a[4];                                         \
    float v3 = (cc & 1) ? a[7] : a[6];                                         \
    float u0 = (cc & 2) ? v1 : v0;                                             \
    float u1 = (cc & 2) ? v3 : v2;                                             \
    float sum = (cc & 4) ? u1 : u0;                                            \
    float h = tanh_fast(sum + xpc);                                            \
    if (writer) {                                                              \
      hs[(P) ^ 1][j] = h;                                                      \
      pcol[(size_t)(S) * BH] = h;                                              \
    }                                                                          \
    xpc = xp1; xp1 = xp2;                                                      \
    LDS_BARRIER();                                                             \
  }

  for (int s = 0; s < T_STEPS; s += 2) {
    STEP(s, 0)
    STEP(s + 1, 1)
  }
#undef STEP
}

extern "C" void kernel_launch(void* const* d_in, const int* in_sizes, int n_in,
                              void* d_out, int out_size, void* d_ws, size_t ws_size,
                              hipStream_t stream) {
  const float* x   = (const float*)d_in[0];
  const float* Wih = (const float*)d_in[1];
  const float* Whh = (const float*)d_in[2];
  const float* bih = (const float*)d_in[3];
  const float* bhh = (const float*)d_in[4];
  float* out = (float*)d_out;

  dim3 g1((T_STEPS * BATCH) / BM, DH / BN);   // 1024 x 2
  xp_gemm<<<g1, dim3(256), 0, stream>>>(x, Wih, bih, bhh, out);
  rnn_rec<<<BATCH, dim3(512), 0, stream>>>(Whh, out);
}